// Round 5
// baseline (357.327 us; speedup 1.0000x reference)
//
#include <hip/hip_runtime.h>
#include <math.h>
#include <stdint.h>

#define HH 256
#define HW 65536
#define CIN 256
#define DLOI 128
#define NLINES 10000
#define LPB 5000
#define NGROUPS 1250

typedef _Float16 h2v  __attribute__((ext_vector_type(2)));
typedef _Float16 f16x8 __attribute__((ext_vector_type(8)));
typedef float    f32x4 __attribute__((ext_vector_type(4)));

__device__ __forceinline__ h2v u2h(unsigned int u) { return __builtin_bit_cast(h2v, u); }
__device__ __forceinline__ unsigned int h2u(h2v h) { return __builtin_bit_cast(unsigned int, h); }
// pkrtz returns __fp16 ext_vector(2); bit_cast via decltype to avoid type mismatch
__device__ __forceinline__ unsigned int pk2u(float a, float b) {
    return __builtin_bit_cast(unsigned int, __builtin_amdgcn_cvt_pkrtz(a, b));
}

__device__ __forceinline__ float fdot2(h2v a, unsigned int w, float c) {
#if __has_builtin(__builtin_amdgcn_fdot2)
    return __builtin_amdgcn_fdot2(a, u2h(w), c, false);
#else
    h2v b = u2h(w);
    return c + (float)a[0] * (float)b[0] + (float)a[1] * (float)b[1];
#endif
}

__device__ __forceinline__ h2v relu2(h2v a) {
    h2v z = (h2v)(_Float16)0.f;
#if __has_builtin(__builtin_elementwise_max)
    return __builtin_elementwise_max(a, z);
#else
    h2v r; r[0] = a[0] > z[0] ? a[0] : z[0]; r[1] = a[1] > z[1] ? a[1] : z[1]; return r;
#endif
}
__device__ __forceinline__ h2v hmax2v(h2v a, h2v b) {
#if __has_builtin(__builtin_elementwise_max)
    return __builtin_elementwise_max(a, b);
#else
    h2v r; r[0] = a[0] > b[0] ? a[0] : b[0]; r[1] = a[1] > b[1] ? a[1] : b[1]; return r;
#endif
}

// ---------------------------------------------------------------------------
// prep_small: zero work counter + f16 weight conversions + per-lane MFMA
// fragment pre-pack of w_fc1 + folded BN packs.
// Wf layout: uint4[ ((ks*2+wm)*4+mt)*64 + lane ], frag elem j =
//   w_fc1[(wm*64+mt*16+(lane&15))*256 + ks*32+(lane>>4)*8 + j]  (f16 RTN).
// ---------------------------------------------------------------------------
__global__ __launch_bounds__(256) void prep_small(
    const float* __restrict__ w_fc1, const float* __restrict__ c1w,
    const float* __restrict__ c2w,  const float* __restrict__ c3w,
    const float* __restrict__ wfc2, const float* __restrict__ bn1,
    const float* __restrict__ bn2,  const float* __restrict__ bn3,
    uint4* __restrict__ Wf4, unsigned int* __restrict__ c1w16,
    unsigned int* __restrict__ c2w16, unsigned int* __restrict__ c3w16,
    unsigned int* __restrict__ wfc2p, unsigned int* __restrict__ bn_pk,
    unsigned int* __restrict__ cnt)
{
    if (blockIdx.x == 0 && threadIdx.x == 0) *cnt = 0;
    int i = blockIdx.x * 256 + threadIdx.x;
    if (i < 4096) {                       // Wf fragment pack
        int lane = i & 63, mt = (i >> 6) & 3, wm = (i >> 8) & 1, ks = i >> 9;
        int row = wm * 64 + mt * 16 + (lane & 15);
        int kb = ks * 32 + (lane >> 4) * 8;
        const float* src = w_fc1 + row * 256 + kb;
        unsigned int q[4];
#pragma unroll
        for (int j2 = 0; j2 < 4; j2++) {
            h2v v = { (_Float16)src[2 * j2], (_Float16)src[2 * j2 + 1] };
            q[j2] = h2u(v);
        }
        uint4 o = { q[0], q[1], q[2], q[3] };
        Wf4[i] = o; return;
    }
    i -= 4096;
    if (i < 4096) {                       // c1w16[c2][o]
        int c2 = i >> 6, o = i & 63;
        h2v v = { (_Float16)c1w[o * 128 + 2 * c2], (_Float16)c1w[o * 128 + 2 * c2 + 1] };
        c1w16[c2 * 64 + o] = h2u(v); return;
    }
    i -= 4096;
    if (i < 6144) {                       // c2w16[i2][tap][o]
        int o = i & 63, rem = i >> 6; int tap = rem % 3, i2 = rem / 3;
        h2v v = { (_Float16)c2w[(o * 64 + 2 * i2) * 3 + tap],
                  (_Float16)c2w[(o * 64 + 2 * i2 + 1) * 3 + tap] };
        c2w16[(i2 * 3 + tap) * 64 + o] = h2u(v); return;
    }
    i -= 6144;
    if (i < 4096) {                       // c3w16[i2][o]
        int o = i & 127, i2 = i >> 7;
        h2v v = { (_Float16)c3w[o * 64 + 2 * i2], (_Float16)c3w[o * 64 + 2 * i2 + 1] };
        c3w16[i2 * 128 + o] = h2u(v); return;
    }
    i -= 4096;
    if (i < 2048) {                       // wfc2p[(j*8+p)*64 + c2]
        int c2 = i & 63, p = (i >> 6) & 7, j = i >> 9;
        h2v v = { (_Float16)wfc2[j * 1024 + (2 * c2) * 8 + p],
                  (_Float16)wfc2[j * 1024 + (2 * c2 + 1) * 8 + p] };
        wfc2p[(j * 8 + p) * 64 + c2] = h2u(v); return;
    }
    i -= 2048;
    if (i < 128) {                        // bn packs
        const float* bn; int C, base, hcount;
        if (i < 64)      { bn = bn1; C = 128; base = 0;   hcount = 64; }
        else if (i < 96) { bn = bn2; C = 64;  base = 128; hcount = 32; i -= 64; }
        else             { bn = bn3; C = 64;  base = 192; hcount = 32; i -= 96; }
        int c0 = 2 * i, c1 = 2 * i + 1;
        float s0 = bn[c0] * rsqrtf(bn[3 * C + c0] + 1e-5f);
        float s1 = bn[c1] * rsqrtf(bn[3 * C + c1] + 1e-5f);
        float h0 = bn[C + c0] - bn[2 * C + c0] * s0;
        float h1 = bn[C + c1] - bn[2 * C + c1] * s1;
        h2v sv = { (_Float16)s0, (_Float16)s1 };
        h2v hv = { (_Float16)h0, (_Float16)h1 };
        bn_pk[base + i] = h2u(sv);
        bn_pk[base + hcount + i] = h2u(hv);
    }
}

// ---------------------------------------------------------------------------
// fc1_v3: streams f32 feature, pkrtz-converts at LDS staging (f16 tile,
// k-pair contiguous, stride 20 u32 for 16B alignment), double-buffered with
// ONE barrier per K-step. W fragments come prepacked from global (L2).
// ---------------------------------------------------------------------------
__global__ __launch_bounds__(256, 4) void fc1_v3(
    const float* __restrict__ feat,   // [B,256,65536]
    const uint4* __restrict__ Wf4,    // prepacked fragments
    const float* __restrict__ bias,
    unsigned int* __restrict__ X)     // [131072][64] h2 units
{
    __shared__ unsigned int Fl[2][128 * 20];   // [pix][kpair], 16 used + 4 pad
    const int t = threadIdx.x;
    const int lane = t & 63, wave = t >> 6;
    const int wm = wave & 1, wn = wave >> 1;
    const int pix0g = blockIdx.x << 7;
    const int b = blockIdx.x >> 9;
    const float* fbase = feat + (size_t)b * (256u * 65536u) + (pix0g & 65535);
    const int cp = t & 15, pg = t >> 4;
    const float* f0 = fbase + (size_t)(2 * cp) * HW + pg * 8;
    const float* f1 = fbase + (size_t)(2 * cp + 1) * HW + pg * 8;

    float4 a0, a1, b0, b1;
    a0 = *(const float4*)(f0);     a1 = *(const float4*)(f0 + 4);
    b0 = *(const float4*)(f1);     b1 = *(const float4*)(f1 + 4);

    f32x4 acc[4][4];
#pragma unroll
    for (int a = 0; a < 4; a++)
#pragma unroll
        for (int c = 0; c < 4; c++) acc[a][c] = (f32x4)0.f;

    auto stage = [&](int buf) {
        unsigned int* w = &Fl[buf][(pg * 8) * 20 + cp];
        w[0]   = pk2u(a0.x, b0.x);
        w[20]  = pk2u(a0.y, b0.y);
        w[40]  = pk2u(a0.z, b0.z);
        w[60]  = pk2u(a0.w, b0.w);
        w[80]  = pk2u(a1.x, b1.x);
        w[100] = pk2u(a1.y, b1.y);
        w[120] = pk2u(a1.z, b1.z);
        w[140] = pk2u(a1.w, b1.w);
    };
    stage(0);

    for (int ks = 0; ks < 8; ks++) {
        // W fragments first (older in vmcnt queue than the prefetch)
        uint4 afu[4];
#pragma unroll
        for (int mt = 0; mt < 4; mt++)
            afu[mt] = Wf4[ks * 512 + wm * 256 + mt * 64 + lane];
        if (ks < 7) {                     // prefetch next K-slab into regs
            const float* g0 = f0 + (size_t)(ks + 1) * 32 * HW;
            const float* g1 = f1 + (size_t)(ks + 1) * 32 * HW;
            a0 = *(const float4*)(g0);     a1 = *(const float4*)(g0 + 4);
            b0 = *(const float4*)(g1);     b1 = *(const float4*)(g1 + 4);
        }
        __syncthreads();                  // Fl[ks&1] fully staged
        const unsigned int* Fb = Fl[ks & 1];
#pragma unroll
        for (int nt = 0; nt < 4; nt++) {
            int pix = wn * 64 + nt * 16 + (lane & 15);
            f16x8 bf = *(const f16x8*)&Fb[pix * 20 + (lane >> 4) * 4];
#pragma unroll
            for (int mt = 0; mt < 4; mt++)
                acc[mt][nt] = __builtin_amdgcn_mfma_f32_16x16x32_f16(
                    __builtin_bit_cast(f16x8, afu[mt]), bf, acc[mt][nt], 0, 0, 0);
        }
        if (ks < 7) stage((ks + 1) & 1);  // other buffer; safe post-barrier
    }

#pragma unroll
    for (int mt = 0; mt < 4; mt++) {
        int o = wm * 64 + mt * 16 + (lane >> 4) * 4;
        float4 b4 = *(const float4*)(bias + o);
#pragma unroll
        for (int nt = 0; nt < 4; nt++) {
            int pix = pix0g + wn * 64 + nt * 16 + (lane & 15);
            f32x4 a = acc[mt][nt];
            h2v lo = { (_Float16)(a[0] + b4.x), (_Float16)(a[1] + b4.y) };
            h2v hi = { (_Float16)(a[2] + b4.z), (_Float16)(a[3] + b4.w) };
            uint2 v = { h2u(lo), h2u(hi) };
            *(uint2*)(X + (size_t)pix * 64 + (o >> 1)) = v;
        }
    }
}

// ---------------------------------------------------------------------------
// line_v4: persistent blocks (1024 = 4/CU) + atomic work-stealing over 1250
// 8-line groups -> zero dispatch raggedness. Body identical to proven v3.
// ---------------------------------------------------------------------------
__global__ __launch_bounds__(256, 4) void line_v4(
    const unsigned int* __restrict__ X,      // [131072][64] h2 units
    const float* __restrict__ lines,
    const unsigned int* __restrict__ c1w16, const float* __restrict__ c1b,
    const unsigned int* __restrict__ c2w16, const float* __restrict__ c2b,
    const unsigned int* __restrict__ c3w16, const float* __restrict__ c3b,
    const unsigned int* __restrict__ wfc2p, const float* __restrict__ bfc2,
    const unsigned int* __restrict__ bn_pk, unsigned int* __restrict__ cnt,
    float* __restrict__ out)
{
    __shared__ int geoB[256];
    __shared__ unsigned int geoWA[256], geoWB[256];
    __shared__ h2v xp[64 * 65];
    __shared__ h2v hb[32 * 65];
    __shared__ h2v ap[32 * 73];
    __shared__ float red[128];
    __shared__ int s_g;

    const int t = threadIdx.x;
    const int col = t & 63;
    const int og = t >> 6;

    for (;;) {
        if (t == 0) s_g = (int)atomicAdd(cnt, 1u);
        __syncthreads();
        const int g = s_g;
        if (g >= NGROUPS) break;
        const int n0 = g * 8;

        // ---- geometry ----
        {
            int l = t >> 5, k = t & 31;
            int n = n0 + l;
            float4 ln = *(const float4*)(lines + n * 4);
            float lam = (float)k / 31.0f;
            float px = ln.x * lam + ln.z * (1.f - lam) - 0.5f;
            float py = ln.y * lam + ln.w * (1.f - lam) - 0.5f;
            float px0 = fminf(fmaxf(floorf(px), 0.f), 255.f);
            float py0 = fminf(fmaxf(floorf(py), 0.f), 255.f);
            float dx = px - px0, dy = py - py0;
            float ex = 1.f - dx, ey = 1.f - dy;
            h2v wA = { (_Float16)(ex * ey), (_Float16)(dx * ey) };
            h2v wB = { (_Float16)(ex * dy), (_Float16)(dx * dy) };
            int b = (n >= LPB) ? 1 : 0;
            int pixflat = (b << 16) + ((int)px0 << 8) + (int)py0;
            geoB[t] = pixflat << 6;
            geoWA[t] = h2u(wA); geoWB[t] = h2u(wB);
        }
        __syncthreads();

        // ---- gather + maxpool4 (uint4 loads) ----
        {
            const int c8 = t & 15;
            const int sub = t >> 4;
            const int line = sub >> 1;
            const int gbase = (sub & 1) * 4;
            const uint4* xq = (const uint4*)X;
#pragma unroll
            for (int lg = 0; lg < 4; lg++) {
                int gi = gbase + lg;
                int ptb = line * 32 + gi * 4;
                h2v m0, m1, m2, m3;
#pragma unroll
                for (int s = 0; s < 4; s++) {
                    int pt = ptb + s;
                    int base4 = (geoB[pt] >> 2) + c8;
                    h2v wA = u2h(geoWA[pt]), wB = u2h(geoWB[pt]);
                    uint4 q00 = xq[base4];
                    uint4 q10 = xq[base4 + 4096];
                    uint4 q01 = xq[base4 + 16];
                    uint4 q11 = xq[base4 + 4112];
                    h2v w00 = { wA[0], wA[0] }, w10 = { wA[1], wA[1] };
                    h2v w01 = { wB[0], wB[0] }, w11 = { wB[1], wB[1] };
                    h2v v0 = u2h(q00.x) * w00 + u2h(q10.x) * w10 + u2h(q01.x) * w01 + u2h(q11.x) * w11;
                    h2v v1 = u2h(q00.y) * w00 + u2h(q10.y) * w10 + u2h(q01.y) * w01 + u2h(q11.y) * w11;
                    h2v v2 = u2h(q00.z) * w00 + u2h(q10.z) * w10 + u2h(q01.z) * w01 + u2h(q11.z) * w11;
                    h2v v3 = u2h(q00.w) * w00 + u2h(q10.w) * w10 + u2h(q01.w) * w01 + u2h(q11.w) * w11;
                    if (s == 0) { m0 = v0; m1 = v1; m2 = v2; m3 = v3; }
                    else { m0 = hmax2v(m0, v0); m1 = hmax2v(m1, v1);
                           m2 = hmax2v(m2, v2); m3 = hmax2v(m3, v3); }
                }
                int colw = line * 8 + gi;
                xp[(c8 * 4 + 0) * 65 + colw] = m0;
                xp[(c8 * 4 + 1) * 65 + colw] = m1;
                xp[(c8 * 4 + 2) * 65 + colw] = m2;
                xp[(c8 * 4 + 3) * 65 + colw] = m3;
            }
        }
        __syncthreads();

        // ---- c1 (128->64), bn1+relu folded ----
        {
            const int obU = __builtin_amdgcn_readfirstlane(og * 16);
            float acc[16];
#pragma unroll
            for (int i = 0; i < 16; i++) acc[i] = c1b[obU + i];
#pragma unroll 8
            for (int c2 = 0; c2 < 64; c2++) {
                h2v sc = u2h(bn_pk[c2]), sh = u2h(bn_pk[64 + c2]);
                h2v av = relu2(xp[c2 * 65 + col] * sc + sh);
                unsigned int wv[16];
#pragma unroll
                for (int q = 0; q < 4; q++)
                    *(uint4*)&wv[q * 4] = *(const uint4*)(c1w16 + c2 * 64 + obU + q * 4);
#pragma unroll
                for (int i = 0; i < 16; i++) acc[i] = fdot2(av, wv[i], acc[i]);
            }
#pragma unroll
            for (int j = 0; j < 8; j++) {
                h2v v = { (_Float16)acc[2 * j], (_Float16)acc[2 * j + 1] };
                hb[(obU / 2 + j) * 65 + col] = v;
            }
        }
        __syncthreads();

        // ---- a2 = relu(bn2(h1)) into padded ap ----
        {
            int c2 = t >> 3, l = t & 7;
            h2v sc = u2h(bn_pk[128 + c2]), sh = u2h(bn_pk[160 + c2]);
            h2v z = (h2v)(_Float16)0.f;
            ap[c2 * 73 + l * 9] = z;
#pragma unroll
            for (int p = 0; p < 8; p++)
                ap[c2 * 73 + l * 9 + 1 + p] = relu2(hb[c2 * 65 + l * 8 + p] * sc + sh);
            if (l == 7) ap[c2 * 73 + 72] = z;
        }
        __syncthreads();

        // ---- c2 conv3 (64->64) ----
        {
            const int obU = __builtin_amdgcn_readfirstlane(og * 16);
            const int l = col >> 3, p = col & 7;
            const int pos0 = l * 9 + p;
            float acc[16];
#pragma unroll
            for (int i = 0; i < 16; i++) acc[i] = c2b[obU + i];
#pragma unroll 2
            for (int i2 = 0; i2 < 32; i2++) {
                h2v aa0 = ap[i2 * 73 + pos0];
                h2v aa1 = ap[i2 * 73 + pos0 + 1];
                h2v aa2 = ap[i2 * 73 + pos0 + 2];
                unsigned int wv[48];
#pragma unroll
                for (int tap = 0; tap < 3; tap++)
#pragma unroll
                    for (int q = 0; q < 4; q++)
                        *(uint4*)&wv[tap * 16 + q * 4] =
                            *(const uint4*)(c2w16 + (i2 * 3 + tap) * 64 + obU + q * 4);
#pragma unroll
                for (int i = 0; i < 16; i++) {
                    acc[i] = fdot2(aa0, wv[i], acc[i]);
                    acc[i] = fdot2(aa1, wv[16 + i], acc[i]);
                    acc[i] = fdot2(aa2, wv[32 + i], acc[i]);
                }
            }
#pragma unroll
            for (int j = 0; j < 8; j++) {
                h2v v = { (_Float16)acc[2 * j], (_Float16)acc[2 * j + 1] };
                hb[(obU / 2 + j) * 65 + col] = v;
            }
        }
        __syncthreads();

        // ---- a3 = relu(bn3(h2)) ----
#pragma unroll
        for (int r = 0; r < 8; r++) {
            int idx = t + 256 * r;
            int c2 = idx >> 6, cl = idx & 63;
            h2v sc = u2h(bn_pk[192 + c2]), sh = u2h(bn_pk[224 + c2]);
            ap[c2 * 64 + cl] = relu2(hb[c2 * 65 + cl] * sc + sh);
        }
        __syncthreads();

        // ---- c3 (64->128) + residual + fc2 partial ----
        {
            const int obU = __builtin_amdgcn_readfirstlane(og * 32);
            float acc[32];
#pragma unroll
            for (int i = 0; i < 32; i++) acc[i] = c3b[obU + i];
#pragma unroll 2
            for (int i2 = 0; i2 < 32; i2++) {
                h2v av = ap[i2 * 64 + col];
                unsigned int wv[32];
#pragma unroll
                for (int q = 0; q < 8; q++)
                    *(uint4*)&wv[q * 4] = *(const uint4*)(c3w16 + i2 * 128 + obU + q * 4);
#pragma unroll
                for (int i = 0; i < 32; i++) acc[i] = fdot2(av, wv[i], acc[i]);
            }
            const int p = col & 7, l = col >> 3;
            h2v yv[16];
#pragma unroll
            for (int j = 0; j < 16; j++) {
                h2v hv = { (_Float16)acc[2 * j], (_Float16)acc[2 * j + 1] };
                yv[j] = relu2(xp[(obU / 2 + j) * 65 + col] + hv);
            }
            float aj[4] = { 0.f, 0.f, 0.f, 0.f };
#pragma unroll
            for (int j = 0; j < 4; j++) {
                unsigned int wv2[16];
#pragma unroll
                for (int q = 0; q < 4; q++)
                    *(uint4*)&wv2[q * 4] = *(const uint4*)(wfc2p + (j * 8 + p) * 64 + obU / 2 + q * 4);
#pragma unroll
                for (int j16 = 0; j16 < 16; j16++) aj[j] = fdot2(yv[j16], wv2[j16], aj[j]);
            }
#pragma unroll
            for (int off = 4; off > 0; off >>= 1) {
#pragma unroll
                for (int j = 0; j < 4; j++) aj[j] += __shfl_down(aj[j], off, 8);
            }
            if ((t & 7) == 0) {
#pragma unroll
                for (int j = 0; j < 4; j++) red[og * 32 + l * 4 + j] = aj[j];
            }
        }
        __syncthreads();

        // ---- final reduce + softmax ----
        if (t < 8) {
            float lg[4];
#pragma unroll
            for (int j = 0; j < 4; j++)
                lg[j] = bfc2[j] + red[t * 4 + j] + red[32 + t * 4 + j]
                      + red[64 + t * 4 + j] + red[96 + t * 4 + j];
            float mx = fmaxf(fmaxf(lg[0], lg[1]), fmaxf(lg[2], lg[3]));
            float e0 = expf(lg[0] - mx), e1 = expf(lg[1] - mx);
            float e2 = expf(lg[2] - mx), e3 = expf(lg[3] - mx);
            float s = 1.f / (e0 + e1 + e2 + e3);
            float4 r = { e0 * s, e1 * s, e2 * s, e3 * s };
            *(float4*)(out + (size_t)(n0 + t) * 4) = r;
        }
        __syncthreads();
    }
}

extern "C" void kernel_launch(void* const* d_in, const int* in_sizes, int n_in,
                              void* d_out, int out_size, void* d_ws, size_t ws_size,
                              hipStream_t stream) {
    const float* feature = (const float*)d_in[0];
    const float* lines   = (const float*)d_in[1];
    const float* w_fc1   = (const float*)d_in[2];
    const float* b_fc1   = (const float*)d_in[3];
    const float* bn1     = (const float*)d_in[4];
    const float* c1_w    = (const float*)d_in[5];
    const float* c1_b    = (const float*)d_in[6];
    const float* bn2     = (const float*)d_in[7];
    const float* c2_w    = (const float*)d_in[8];
    const float* c2_b    = (const float*)d_in[9];
    const float* bn3     = (const float*)d_in[10];
    const float* c3_w    = (const float*)d_in[11];
    const float* c3_b    = (const float*)d_in[12];
    const float* w_fc2   = (const float*)d_in[13];
    const float* b_fc2   = (const float*)d_in[14];
    float* out = (float*)d_out;

    char* ws = (char*)d_ws;
    unsigned int* X     = (unsigned int*)ws;                 // 33,554,432 B
    uint4*        Wf4   = (uint4*)(ws + 33554432);           // 65,536 B
    unsigned int* c1w16 = (unsigned int*)(ws + 33619968);    // 16,384 B
    unsigned int* c2w16 = (unsigned int*)(ws + 33636352);    // 24,576 B
    unsigned int* c3w16 = (unsigned int*)(ws + 33660928);    // 16,384 B
    unsigned int* wfc2p = (unsigned int*)(ws + 33677312);    // 8,192 B
    unsigned int* bn_pk = (unsigned int*)(ws + 33685504);    // 1,024 B
    unsigned int* cnt   = (unsigned int*)(ws + 33686528);    // 4 B

    prep_small<<<81, 256, 0, stream>>>(w_fc1, c1_w, c2_w, c3_w, w_fc2, bn1, bn2, bn3,
                                       Wf4, c1w16, c2w16, c3w16, wfc2p, bn_pk, cnt);
    fc1_v3<<<1024, 256, 0, stream>>>(feature, Wf4, b_fc1, X);
    line_v4<<<1024, 256, 0, stream>>>(X, lines, c1w16, c1_b, c2w16, c2_b,
                                      c3w16, c3_b, wfc2p, b_fc2, bn_pk, cnt, out);
}